// Round 4
// baseline (3749.412 us; speedup 1.0000x reference)
//
#include <hip/hip_runtime.h>
#include <math.h>

// UNISURF renderer, MI355X. One wave (64 lanes) per ray; 4 rays per 256-thread
// block. Layer-2 weights are read with WAVE-UNIFORM addresses from global
// memory so the compiler scalarizes them (s_load -> SGPR operand of v_fmac),
// keeping the LDS pipe free. LDS holds only per-ray u/v (broadcast b128) and
// a copy of W2 for the lane-parallel secant evals.
//
// R3 -> R4: __launch_bounds__(256,2) -> (256,1). R3 counters showed the
// allocator capped at 128 VGPR and spilled h1[128] (WRITE_SIZE 305 MB of
// scratch writeback, VALUBusy 19%). (256,1) raises the VGPR cap to 512 so
// h1 stays in registers; actual use ~200 -> still 2 waves/SIMD at runtime.

#define HID 128

__device__ __forceinline__ float sigmoidf_(float x) {
    return 1.0f / (1.0f + expf(-x));
}

// Layer2 + heads for one sample at depth d. h1 in 128 VGPRs (static indices).
// Weight operands are wave-uniform global loads -> scalar pipe.
template<bool RGB>
__device__ __forceinline__ void mlp_eval(
    const float* su, const float* sv,                 // LDS (per-ray u, v)
    const float* __restrict__ gW2, const float* __restrict__ gB2,
    const float* __restrict__ gWo, const float* __restrict__ gWc,
    float d, float bo0, float& logit_out, float* rgb_out)
{
    float h1[HID];
#pragma unroll
    for (int k = 0; k < HID; k += 4) {
        float4 u = *reinterpret_cast<const float4*>(su + k);
        float4 v = *reinterpret_cast<const float4*>(sv + k);
        h1[k + 0] = fmaxf(fmaf(d, v.x, u.x), 0.f);
        h1[k + 1] = fmaxf(fmaf(d, v.y, u.y), 0.f);
        h1[k + 2] = fmaxf(fmaf(d, v.z, u.z), 0.f);
        h1[k + 3] = fmaxf(fmaf(d, v.w, u.w), 0.f);
    }
    float lg = 0.f, r0 = 0.f, r1 = 0.f, r2 = 0.f;
#pragma unroll 1   // keep jb rolled: body = 128 uniform dwordx4 loads + 512 FMA
    for (int jb = 0; jb < 32; ++jb) {
        const float4* wq = reinterpret_cast<const float4*>(gW2 + jb * 4); // [k] stride 32 float4
        float a0 = 0.f, a1 = 0.f, a2 = 0.f, a3 = 0.f;
#pragma unroll
        for (int k = 0; k < HID; ++k) {
            const float4 wv = wq[k * 32];          // wave-uniform -> s_load_dwordx4
            a0 = fmaf(h1[k], wv.x, a0);
            a1 = fmaf(h1[k], wv.y, a1);
            a2 = fmaf(h1[k], wv.z, a2);
            a3 = fmaf(h1[k], wv.w, a3);
        }
        const float4 bb = *reinterpret_cast<const float4*>(gB2 + jb * 4);
        const float4 wo = *reinterpret_cast<const float4*>(gWo + jb * 4);
        const float h20 = fmaxf(a0 + bb.x, 0.f);
        const float h21 = fmaxf(a1 + bb.y, 0.f);
        const float h22 = fmaxf(a2 + bb.z, 0.f);
        const float h23 = fmaxf(a3 + bb.w, 0.f);
        lg = fmaf(h20, wo.x, lg);
        lg = fmaf(h21, wo.y, lg);
        lg = fmaf(h22, wo.z, lg);
        lg = fmaf(h23, wo.w, lg);
        if (RGB) {
            const float4* wc4 = reinterpret_cast<const float4*>(gWc + jb * 12);
            const float4 wa = wc4[0], wb = wc4[1], wc = wc4[2];
            r0 = fmaf(h20, wa.x, r0);  r1 = fmaf(h20, wa.y, r1);  r2 = fmaf(h20, wa.z, r2);
            r0 = fmaf(h21, wa.w, r0);  r1 = fmaf(h21, wb.x, r1);  r2 = fmaf(h21, wb.y, r2);
            r0 = fmaf(h22, wb.z, r0);  r1 = fmaf(h22, wb.w, r1);  r2 = fmaf(h22, wc.x, r2);
            r0 = fmaf(h23, wc.y, r0);  r1 = fmaf(h23, wc.z, r1);  r2 = fmaf(h23, wc.w, r2);
        }
    }
    logit_out = lg + bo0;
    if (RGB) { rgb_out[0] = r0; rgb_out[1] = r1; rgb_out[2] = r2; }
}

extern "C" __global__ void __launch_bounds__(256, 1)
unisurf_render_kernel(
    const float* __restrict__ raysDir, const float* __restrict__ raysOrg,
    const float* __restrict__ W1, const float* __restrict__ b1,
    const float* __restrict__ W2, const float* __restrict__ b2,
    const float* __restrict__ Wo, const float* __restrict__ bo,
    const float* __restrict__ Wc, const float* __restrict__ bc,
    const int* __restrict__ itp,
    float* __restrict__ outRGB, float* __restrict__ outD, float* __restrict__ outM,
    int nRays)
{
    __shared__ __align__(16) float sW2[HID * HID];   // [k][j] row-major; secant only
    __shared__ __align__(16) float sB2[HID];
    __shared__ __align__(16) float sWo[HID];
    __shared__ __align__(16) float sU[4][HID];
    __shared__ __align__(16) float sV[4][HID];
    __shared__ __align__(16) float sH1[4][HID];

    const int tid = threadIdx.x;
    {   // stage W2 for the secant path: 4096 float4, coalesced
        const float4* g = reinterpret_cast<const float4*>(W2);
        float4* s = reinterpret_cast<float4*>(sW2);
#pragma unroll
        for (int i = 0; i < 16; ++i) s[tid + i * 256] = g[tid + i * 256];
    }
    if (tid < HID) { sB2[tid] = b2[tid]; sWo[tid] = Wo[tid]; }
    __syncthreads();

    const int w = tid >> 6, lane = tid & 63;
    const int ray = blockIdx.x * 4 + w;
    if (ray >= nRays) return;

    // ---- per-ray setup -----------------------------------------------------
    const float ox = raysOrg[ray * 3 + 0], oy = raysOrg[ray * 3 + 1], oz = raysOrg[ray * 3 + 2];
    const float dx = raysDir[ray * 3 + 0], dy = raysDir[ray * 3 + 1], dz = raysDir[ray * 3 + 2];
    const float nrm = sqrtf(dx * dx + dy * dy + dz * dz);
    const float rdx = dx / nrm, rdy = dy / nrm, rdz = dz / nrm;
    const float bo0 = bo[0];

    float* su = sU[w];
    float* sv = sV[w];
    float* sh = sH1[w];
    for (int k = lane; k < HID; k += 64) {
        const float w1x = W1[k], w1y = W1[HID + k], w1z = W1[2 * HID + k];
        su[k] = ox * w1x + oy * w1y + oz * w1z + b1[k];
        sv[k] = rdx * w1x + rdy * w1y + rdz * w1z;
    }
    asm volatile("s_waitcnt lgkmcnt(0)" ::: "memory");
    __builtin_amdgcn_sched_barrier(0);

    const float STEP = 1.0f / 127.0f;   // linspace(NEAR,FAR,128) step

    // ---- marching: chunk A (steps 0..63) -----------------------------------
    float fA;
    {
        float lg;
        mlp_eval<false>(su, sv, W2, b2, Wo, Wc, 0.8f + (float)lane * STEP, bo0, lg, nullptr);
        fA = sigmoidf_(lg) - 0.5f;
    }
    const float f0 = __shfl(fA, 0);
    const float fAn = __shfl_down(fA, 1);
    const bool crossA = (lane < 63) && (fA * fAn < 0.f);
    const unsigned long long balA = __ballot(crossA);

    int idx = 0; float f_lo = 0.f, f_hi = 0.f; bool haschange = false;
    if (balA) {
        const int l = __ffsll(balA) - 1;
        idx = l; f_lo = __shfl(fA, l); f_hi = __shfl(fA, l + 1); haschange = true;
    } else if (f0 < 0.f) {
        // ---- chunk B (steps 64..127), only if it can still matter ----------
        float fB;
        {
            float lg;
            mlp_eval<false>(su, sv, W2, b2, Wo, Wc, 0.8f + (float)(64 + lane) * STEP, bo0, lg, nullptr);
            fB = sigmoidf_(lg) - 0.5f;
        }
        float fprev = __shfl_up(fB, 1);
        const float fA63 = __shfl(fA, 63);
        if (lane == 0) fprev = fA63;
        const bool crossB = (fprev * fB < 0.f);   // pair s = 63 + lane
        const unsigned long long balB = __ballot(crossB);
        if (balB) {
            const int l = __ffsll(balB) - 1;
            idx = 63 + l; f_lo = __shfl(fprev, l); f_hi = __shfl(fB, l); haschange = true;
        }
    }

    // ---- secant refinement (wave-uniform control) --------------------------
    float d_i;
    bool objmask = false;
    if (f0 >= 0.f) {
        d_i = 0.f;                       // ray starts inside -> mask_zero
    } else if (haschange && (f_lo < 0.f)) {
        float dlo = 0.8f + (float)idx * STEP;
        float dhi = 0.8f + (float)(idx + 1) * STEP;
        float flo = f_lo, fhi = f_hi;
        for (int itn = 0; itn < 8; ++itn) {
            float den = fhi - flo;
            if (fabsf(den) < 1e-12f) den = 1e-12f;
            const float dmid = dlo - flo * (dhi - dlo) / den;
            // lane-parallel MLP eval at dmid: h1 via LDS, j split across lanes
            for (int k = lane; k < HID; k += 64)
                sh[k] = fmaxf(fmaf(dmid, sv[k], su[k]), 0.f);
            asm volatile("s_waitcnt lgkmcnt(0)" ::: "memory");
            __builtin_amdgcn_sched_barrier(0);
            float a0 = 0.f, a1 = 0.f;
#pragma unroll 4
            for (int k = 0; k < HID; ++k) {
                const float hk = sh[k];
                a0 = fmaf(hk, sW2[k * HID + lane], a0);
                a1 = fmaf(hk, sW2[k * HID + lane + 64], a1);
            }
            const float h2a = fmaxf(a0 + sB2[lane], 0.f);
            const float h2b = fmaxf(a1 + sB2[lane + 64], 0.f);
            float part = h2a * sWo[lane] + h2b * sWo[lane + 64];
#pragma unroll
            for (int off = 32; off; off >>= 1) part += __shfl_xor(part, off);
            const float fmid = sigmoidf_(part + bo0) - 0.5f;
            if (fmid < 0.f) { dlo = dmid; flo = fmid; }
            else            { dhi = dmid; fhi = fmid; }
        }
        float den = fhi - flo;
        if (fabsf(den) < 1e-12f) den = 1e-12f;
        d_i = dlo - flo * (dhi - dlo) / den;
        objmask = true;                  // finite & nonzero
    } else {
        d_i = __builtin_inff();          // miss
    }

    // ---- render: 64 samples, lane = sample ---------------------------------
    const int it = itp[0];
    const float delta = fmaxf(0.1f * expf(-2e-5f * (float)it), 0.01f);
    const float dsafe = objmask ? d_i : 1.0f;
    const float dnp = fmaxf(dsafe - delta, 0.8f);
    const float dfp = fminf(dsafe + delta, 1.8f);
    const float t = (float)lane * (1.0f / 63.0f);
    const float depth = objmask ? (dnp * (1.f - t) + dfp * t)
                                : (0.8f * (1.f - t) + 1.8f * t);

    float lg, rgbacc[3];
    mlp_eval<true>(su, sv, W2, b2, Wo, Wc, depth, bo0, lg, rgbacc);
    const float alpha = sigmoidf_(lg);
    float rc[3];
#pragma unroll
    for (int c = 0; c < 3; ++c) {
        const float x = rgbacc[c]
            + rdx * Wc[128 * 3 + c] + rdy * Wc[129 * 3 + c] + rdz * Wc[130 * 3 + c]
            + bc[c];
        rc[c] = sigmoidf_(x);
    }

    // transmittance: exclusive prefix product of (1 - alpha + 1e-6) over lanes
    const float om = 1.f - alpha + 1e-6f;
    float incl = om;
#pragma unroll
    for (int off = 1; off < 64; off <<= 1) {
        const float p = __shfl_up(incl, off);
        if (lane >= off) incl *= p;
    }
    float trans = __shfl_up(incl, 1);
    if (lane == 0) trans = 1.f;
    const float wgt = alpha * trans;

    float s0 = wgt * rc[0], s1 = wgt * rc[1], s2 = wgt * rc[2], sd = wgt * depth;
#pragma unroll
    for (int off = 32; off; off >>= 1) {
        s0 += __shfl_xor(s0, off);
        s1 += __shfl_xor(s1, off);
        s2 += __shfl_xor(s2, off);
        sd += __shfl_xor(sd, off);
    }
    if (lane == 0) {
        outRGB[ray * 3 + 0] = s0;
        outRGB[ray * 3 + 1] = s1;
        outRGB[ray * 3 + 2] = s2;
        outD[ray] = sd;
        outM[ray] = objmask ? 1.f : 0.f;
    }
}

extern "C" void kernel_launch(void* const* d_in, const int* in_sizes, int n_in,
                              void* d_out, int out_size, void* d_ws, size_t ws_size,
                              hipStream_t stream) {
    (void)n_in; (void)out_size; (void)d_ws; (void)ws_size;
    const int R = in_sizes[0] / 3;   // total rays (B*N)
    float* out = reinterpret_cast<float*>(d_out);
    dim3 grid((R + 3) / 4), block(256);
    hipLaunchKernelGGL(unisurf_render_kernel, grid, block, 0, stream,
        (const float*)d_in[0], (const float*)d_in[1], (const float*)d_in[2],
        (const float*)d_in[3], (const float*)d_in[4], (const float*)d_in[5],
        (const float*)d_in[6], (const float*)d_in[7], (const float*)d_in[8],
        (const float*)d_in[9], (const int*)d_in[10],
        out, out + 3 * (size_t)R, out + 4 * (size_t)R, R);
}

// Round 5
// 343.720 us; speedup vs baseline: 10.9083x; 10.9083x over previous
//
#include <hip/hip_runtime.h>
#include <math.h>

// UNISURF renderer, MI355X — MFMA edition.
// One wave per ray; 4 rays / 256-thread block. Each heavy eval (64 samples x
// 128->128->heads MLP) is a per-wave GEMM on v_mfma_f32_16x16x32_bf16 with a
// 3-pass hi/lo bf16 split (AhBh + AlBh + AhBl) for ~f32 accuracy.
// W2 is pre-packed ONCE per block into MFMA B-fragment order in LDS (hi+lo),
// so the K-loop reads one ds_read_b128 per fragment. A-fragments are built
// in-register from per-ray u,v (h1 = relu(u + d*v)).
//
// Layout assumptions (v_mfma_f32_16x16x32_bf16, gfx950):
//   A: row = lane&15,  k = 4*(lane>>4) + (e&3) + 16*(e>>2)   (e = 0..7)
//   B: col = lane&15,  same k-map (CDNA3 16x16x16 doubled as two K=16 halves)
//   C: col = lane&15,  row = 4*(lane>>4) + reg               (m89-verified)

#define HID 128
#define NEARF 0.8f
#define FARF  1.8f
#define STEP  (1.0f f_unused)
static __device__ __forceinline__ float step_() { return 1.0f / 127.0f; }

typedef __attribute__((ext_vector_type(8))) short short8_t;
typedef __attribute__((ext_vector_type(4))) float f32x4;
typedef __attribute__((ext_vector_type(4))) int   int4_t;

__device__ __forceinline__ float sigmoidf_(float x) { return 1.0f / (1.0f + expf(-x)); }
__device__ __forceinline__ unsigned fbits(float x) { return __builtin_bit_cast(unsigned, x); }
__device__ __forceinline__ float bitsf(unsigned x) { return __builtin_bit_cast(float, x); }
// round-to-nearest-even f32 -> bf16 (returns low-16 bits)
__device__ __forceinline__ unsigned rne16(float x) {
    unsigned r = fbits(x);
    return (r + 0x7fffu + ((r >> 16) & 1u)) >> 16;
}

// 64-sample MLP eval on MFMA. dA0..3 = depth of sample (mt*16 + lane&15).
// Returns raw logit (no bo) in f_out[lane] and, if RGB, feat@Wc partial sums.
template<bool RGB>
__device__ __forceinline__ void eval64(
    const float* __restrict__ su, const float* __restrict__ sv,
    const short* __restrict__ sW2H, const short* __restrict__ sW2L,
    const float* __restrict__ sB2, const float* __restrict__ sWo,
    const float* __restrict__ sWc, float* __restrict__ sred,
    float dA0, float dA1, float dA2, float dA3, int lane,
    float& f_out, float* rgb_out)
{
    const int g = lane >> 4, nl = lane & 15;
    f32x4 acc[4][8];
#pragma unroll
    for (int mt = 0; mt < 4; ++mt)
#pragma unroll
        for (int nt = 0; nt < 8; ++nt) acc[mt][nt] = (f32x4){0.f, 0.f, 0.f, 0.f};

#pragma unroll
    for (int kt = 0; kt < 4; ++kt) {
        const float* uk = su + kt * 32 + 4 * g;
        const float* vk = sv + kt * 32 + 4 * g;
        const float4 u0 = *reinterpret_cast<const float4*>(uk);
        const float4 u1 = *reinterpret_cast<const float4*>(uk + 16);
        const float4 v0 = *reinterpret_cast<const float4*>(vk);
        const float4 v1 = *reinterpret_cast<const float4*>(vk + 16);
        const float ue[8] = {u0.x, u0.y, u0.z, u0.w, u1.x, u1.y, u1.z, u1.w};
        const float ve[8] = {v0.x, v0.y, v0.z, v0.w, v1.x, v1.y, v1.z, v1.w};
        short8_t Ah[4], Al[4];
#pragma unroll
        for (int mt = 0; mt < 4; ++mt) {
            const float d = (mt == 0) ? dA0 : (mt == 1) ? dA1 : (mt == 2) ? dA2 : dA3;
            int4_t hp, lp;
#pragma unroll
            for (int ep = 0; ep < 4; ++ep) {
                const float h0 = fmaxf(fmaf(d, ve[2 * ep], ue[2 * ep]), 0.f);
                const float h1 = fmaxf(fmaf(d, ve[2 * ep + 1], ue[2 * ep + 1]), 0.f);
                const unsigned b0 = fbits(h0) & 0xffff0000u;
                const unsigned b1 = fbits(h1) & 0xffff0000u;
                hp[ep] = (int)(b1 | (b0 >> 16));
                lp[ep] = (int)((rne16(h1 - bitsf(b1)) << 16) | rne16(h0 - bitsf(b0)));
            }
            Ah[mt] = __builtin_bit_cast(short8_t, hp);
            Al[mt] = __builtin_bit_cast(short8_t, lp);
        }
#pragma unroll
        for (int nt = 0; nt < 8; ++nt) {
            const int frag = (kt * 8 + nt) * 64 + lane;
            const short8_t Bh = *reinterpret_cast<const short8_t*>(&sW2H[frag * 8]);
            const short8_t Bl = *reinterpret_cast<const short8_t*>(&sW2L[frag * 8]);
#pragma unroll
            for (int mt = 0; mt < 4; ++mt) {
                acc[mt][nt] = __builtin_amdgcn_mfma_f32_16x16x32_bf16(Ah[mt], Bh, acc[mt][nt], 0, 0, 0);
                acc[mt][nt] = __builtin_amdgcn_mfma_f32_16x16x32_bf16(Al[mt], Bh, acc[mt][nt], 0, 0, 0);
                acc[mt][nt] = __builtin_amdgcn_mfma_f32_16x16x32_bf16(Ah[mt], Bl, acc[mt][nt], 0, 0, 0);
            }
        }
    }

    // second layer + heads: h2 = relu(G + b2); logit += h2*Wo; rgb += h2*Wc
    float pl[4][4], p0[4][4], p1[4][4], p2[4][4];
#pragma unroll
    for (int mt = 0; mt < 4; ++mt)
#pragma unroll
        for (int r = 0; r < 4; ++r) { pl[mt][r] = 0.f; if (RGB) { p0[mt][r] = 0.f; p1[mt][r] = 0.f; p2[mt][r] = 0.f; } }
#pragma unroll
    for (int nt = 0; nt < 8; ++nt) {
        const int j = nt * 16 + nl;
        const float b2l = sB2[j], wol = sWo[j];
        float wc0 = 0.f, wc1 = 0.f, wc2 = 0.f;
        if (RGB) { wc0 = sWc[j * 3 + 0]; wc1 = sWc[j * 3 + 1]; wc2 = sWc[j * 3 + 2]; }
#pragma unroll
        for (int mt = 0; mt < 4; ++mt)
#pragma unroll
            for (int r = 0; r < 4; ++r) {
                const float h2 = fmaxf(acc[mt][nt][r] + b2l, 0.f);
                pl[mt][r] = fmaf(h2, wol, pl[mt][r]);
                if (RGB) {
                    p0[mt][r] = fmaf(h2, wc0, p0[mt][r]);
                    p1[mt][r] = fmaf(h2, wc1, p1[mt][r]);
                    p2[mt][r] = fmaf(h2, wc2, p2[mt][r]);
                }
            }
    }
    // reduce over the 16 lanes that share a row-group (j varies across them)
#pragma unroll
    for (int off = 1; off < 16; off <<= 1) {
#pragma unroll
        for (int mt = 0; mt < 4; ++mt)
#pragma unroll
            for (int r = 0; r < 4; ++r) {
                pl[mt][r] += __shfl_xor(pl[mt][r], off);
                if (RGB) {
                    p0[mt][r] += __shfl_xor(p0[mt][r], off);
                    p1[mt][r] += __shfl_xor(p1[mt][r], off);
                    p2[mt][r] += __shfl_xor(p2[mt][r], off);
                }
            }
    }
    // scatter to lane order via LDS (row m = mt*16 + 4*g + r)
    if (nl == 0) {
#pragma unroll
        for (int mt = 0; mt < 4; ++mt)
#pragma unroll
            for (int r = 0; r < 4; ++r) {
                const int m = mt * 16 + 4 * g + r;
                sred[m] = pl[mt][r];
                if (RGB) { sred[64 + m] = p0[mt][r]; sred[128 + m] = p1[mt][r]; sred[192 + m] = p2[mt][r]; }
            }
    }
    f_out = sred[lane];
    if (RGB) { rgb_out[0] = sred[64 + lane]; rgb_out[1] = sred[128 + lane]; rgb_out[2] = sred[192 + lane]; }
}

extern "C" __global__ void __launch_bounds__(256, 1)
unisurf_mfma_kernel(
    const float* __restrict__ raysDir, const float* __restrict__ raysOrg,
    const float* __restrict__ W1, const float* __restrict__ b1,
    const float* __restrict__ W2, const float* __restrict__ b2,
    const float* __restrict__ Wo, const float* __restrict__ bo,
    const float* __restrict__ Wc, const float* __restrict__ bc,
    const int* __restrict__ itp,
    float* __restrict__ outRGB, float* __restrict__ outD, float* __restrict__ outM,
    int nRays)
{
    __shared__ __align__(16) short sW2H[2048 * 8];   // B-frag layout, hi bf16 (32KB)
    __shared__ __align__(16) short sW2L[2048 * 8];   // lo bf16 (32KB)
    __shared__ __align__(16) float sU[4][HID];
    __shared__ __align__(16) float sV[4][HID];
    __shared__ __align__(16) float sH1[4][HID];
    __shared__ __align__(16) float sB2[HID];
    __shared__ __align__(16) float sWoS[HID];
    __shared__ __align__(16) float sWc[HID * 3];
    __shared__ __align__(16) float sRed[4][256];

    const int tid = threadIdx.x;
    // ---- stage W2 into MFMA B-fragment order, hi/lo bf16 -------------------
    for (int s = tid; s < 2048; s += 256) {
        const int ln = s & 63, nt = (s >> 6) & 7, kt = s >> 9;
        const int n = nt * 16 + (ln & 15), gg = ln >> 4;
        int4_t hp, lp;
#pragma unroll
        for (int ep = 0; ep < 4; ++ep) {
            const int e0 = 2 * ep, e1 = 2 * ep + 1;
            const int k0 = kt * 32 + 4 * gg + (e0 & 3) + ((e0 >> 2) << 4);
            const int k1 = kt * 32 + 4 * gg + (e1 & 3) + ((e1 >> 2) << 4);
            const float w0 = W2[k0 * HID + n], w1 = W2[k1 * HID + n];
            const unsigned h0 = fbits(w0) & 0xffff0000u;
            const unsigned h1 = fbits(w1) & 0xffff0000u;
            hp[ep] = (int)(h1 | (h0 >> 16));
            lp[ep] = (int)((rne16(w1 - bitsf(h1)) << 16) | rne16(w0 - bitsf(h0)));
        }
        *reinterpret_cast<int4_t*>(&sW2H[s * 8]) = hp;
        *reinterpret_cast<int4_t*>(&sW2L[s * 8]) = lp;
    }
    if (tid < HID) { sB2[tid] = b2[tid]; sWoS[tid] = Wo[tid]; }
    for (int i = tid; i < HID * 3; i += 256) sWc[i] = Wc[i];
    __syncthreads();

    const int w = tid >> 6, lane = tid & 63, nl = lane & 15;
    const int ray = blockIdx.x * 4 + w;
    if (ray >= nRays) return;

    // ---- per-ray setup -----------------------------------------------------
    const float ox = raysOrg[ray * 3 + 0], oy = raysOrg[ray * 3 + 1], oz = raysOrg[ray * 3 + 2];
    const float dx = raysDir[ray * 3 + 0], dy = raysDir[ray * 3 + 1], dz = raysDir[ray * 3 + 2];
    const float nrm = sqrtf(dx * dx + dy * dy + dz * dz);
    const float rdx = dx / nrm, rdy = dy / nrm, rdz = dz / nrm;
    const float bo0 = bo[0];
    const float ST = step_();

    float* su = sU[w];
    float* sv = sV[w];
    float* sh = sH1[w];
    float* sred = sRed[w];
    for (int k = lane; k < HID; k += 64) {
        const float w1x = W1[k], w1y = W1[HID + k], w1z = W1[2 * HID + k];
        su[k] = ox * w1x + oy * w1y + oz * w1z + b1[k];
        sv[k] = rdx * w1x + rdy * w1y + rdz * w1z;
    }
    // (ds in-order per wave + compiler waitcnts make su/sv visible to reads below)

    // ---- marching: chunk A (samples 0..63) ---------------------------------
    float fA;
    {
        float lg;
        const float b0 = NEARF;
        eval64<false>(su, sv, sW2H, sW2L, sB2, sWoS, sWc, sred,
                      b0 + (float)(0 * 16 + nl) * ST, b0 + (float)(1 * 16 + nl) * ST,
                      b0 + (float)(2 * 16 + nl) * ST, b0 + (float)(3 * 16 + nl) * ST,
                      lane, lg, nullptr);
        fA = sigmoidf_(lg + bo0) - 0.5f;
    }
    const float f0 = __shfl(fA, 0);
    const float fAn = __shfl_down(fA, 1);
    const bool crossA = (lane < 63) && (fA * fAn < 0.f);
    const unsigned long long balA = __ballot(crossA);

    int idx = 0; float f_lo = 0.f, f_hi = 0.f; bool haschange = false;
    if (balA) {
        const int l = __ffsll(balA) - 1;
        idx = l; f_lo = __shfl(fA, l); f_hi = __shfl(fA, l + 1); haschange = true;
    } else if (f0 < 0.f) {
        // ---- chunk B (samples 64..127) -------------------------------------
        float fB;
        {
            float lg;
            const float b0 = NEARF + 64.0f * ST;
            eval64<false>(su, sv, sW2H, sW2L, sB2, sWoS, sWc, sred,
                          b0 + (float)(0 * 16 + nl) * ST, b0 + (float)(1 * 16 + nl) * ST,
                          b0 + (float)(2 * 16 + nl) * ST, b0 + (float)(3 * 16 + nl) * ST,
                          lane, lg, nullptr);
            fB = sigmoidf_(lg + bo0) - 0.5f;
        }
        float fprev = __shfl_up(fB, 1);
        const float fA63 = __shfl(fA, 63);
        if (lane == 0) fprev = fA63;
        const bool crossB = (fprev * fB < 0.f);   // pair s = 63 + lane
        const unsigned long long balB = __ballot(crossB);
        if (balB) {
            const int l = __ffsll(balB) - 1;
            idx = 63 + l; f_lo = __shfl(fprev, l); f_hi = __shfl(fB, l); haschange = true;
        }
    }

    // ---- secant refinement (wave-uniform; f32, W2 from global/L2) ----------
    float d_i;
    bool objmask = false;
    if (f0 >= 0.f) {
        d_i = 0.f;
    } else if (haschange && (f_lo < 0.f)) {
        float dlo = NEARF + (float)idx * ST;
        float dhi = NEARF + (float)(idx + 1) * ST;
        float flo = f_lo, fhi = f_hi;
        for (int itn = 0; itn < 8; ++itn) {
            float den = fhi - flo;
            if (fabsf(den) < 1e-12f) den = 1e-12f;
            const float dmid = dlo - flo * (dhi - dlo) / den;
            for (int k = lane; k < HID; k += 64)
                sh[k] = fmaxf(fmaf(dmid, sv[k], su[k]), 0.f);
            asm volatile("s_waitcnt lgkmcnt(0)" ::: "memory");
            __builtin_amdgcn_sched_barrier(0);
            float a0 = 0.f, a1 = 0.f;
#pragma unroll 4
            for (int k = 0; k < HID; ++k) {
                const float hk = sh[k];
                a0 = fmaf(hk, W2[k * HID + lane], a0);
                a1 = fmaf(hk, W2[k * HID + lane + 64], a1);
            }
            const float h2a = fmaxf(a0 + sB2[lane], 0.f);
            const float h2b = fmaxf(a1 + sB2[lane + 64], 0.f);
            float part = h2a * sWoS[lane] + h2b * sWoS[lane + 64];
#pragma unroll
            for (int off = 32; off; off >>= 1) part += __shfl_xor(part, off);
            const float fmid = sigmoidf_(part + bo0) - 0.5f;
            if (fmid < 0.f) { dlo = dmid; flo = fmid; }
            else            { dhi = dmid; fhi = fmid; }
        }
        float den = fhi - flo;
        if (fabsf(den) < 1e-12f) den = 1e-12f;
        d_i = dlo - flo * (dhi - dlo) / den;
        objmask = true;
    } else {
        d_i = __builtin_inff();
    }

    // ---- render: 64 samples, lane = sample ---------------------------------
    const int it = itp[0];
    const float delta = fmaxf(0.1f * expf(-2e-5f * (float)it), 0.01f);
    const float dsafe = objmask ? d_i : 1.0f;
    const float dnp = fmaxf(dsafe - delta, NEARF);
    const float dfp = fminf(dsafe + delta, FARF);
    const float t = (float)lane * (1.0f / 63.0f);
    const float depth = objmask ? (dnp * (1.f - t) + dfp * t)
                                : (NEARF * (1.f - t) + FARF * t);

    float lg, rgbacc[3];
    {
        const float dR0 = __shfl(depth, 0 * 16 + nl);
        const float dR1 = __shfl(depth, 1 * 16 + nl);
        const float dR2 = __shfl(depth, 2 * 16 + nl);
        const float dR3 = __shfl(depth, 3 * 16 + nl);
        eval64<true>(su, sv, sW2H, sW2L, sB2, sWoS, sWc, sred,
                     dR0, dR1, dR2, dR3, lane, lg, rgbacc);
    }
    const float alpha = sigmoidf_(lg + bo0);
    float rc[3];
#pragma unroll
    for (int c = 0; c < 3; ++c) {
        const float x = rgbacc[c]
            + rdx * Wc[128 * 3 + c] + rdy * Wc[129 * 3 + c] + rdz * Wc[130 * 3 + c]
            + bc[c];
        rc[c] = sigmoidf_(x);
    }

    // transmittance: exclusive prefix product of (1 - alpha + 1e-6)
    const float om = 1.f - alpha + 1e-6f;
    float incl = om;
#pragma unroll
    for (int off = 1; off < 64; off <<= 1) {
        const float p = __shfl_up(incl, off);
        if (lane >= off) incl *= p;
    }
    float trans = __shfl_up(incl, 1);
    if (lane == 0) trans = 1.f;
    const float wgt = alpha * trans;

    float s0 = wgt * rc[0], s1 = wgt * rc[1], s2 = wgt * rc[2], sd = wgt * depth;
#pragma unroll
    for (int off = 32; off; off >>= 1) {
        s0 += __shfl_xor(s0, off);
        s1 += __shfl_xor(s1, off);
        s2 += __shfl_xor(s2, off);
        sd += __shfl_xor(sd, off);
    }
    if (lane == 0) {
        outRGB[ray * 3 + 0] = s0;
        outRGB[ray * 3 + 1] = s1;
        outRGB[ray * 3 + 2] = s2;
        outD[ray] = sd;
        outM[ray] = objmask ? 1.f : 0.f;
    }
}

extern "C" void kernel_launch(void* const* d_in, const int* in_sizes, int n_in,
                              void* d_out, int out_size, void* d_ws, size_t ws_size,
                              hipStream_t stream) {
    (void)n_in; (void)out_size; (void)d_ws; (void)ws_size;
    const int R = in_sizes[0] / 3;
    float* out = reinterpret_cast<float*>(d_out);
    dim3 grid((R + 3) / 4), block(256);
    hipLaunchKernelGGL(unisurf_mfma_kernel, grid, block, 0, stream,
        (const float*)d_in[0], (const float*)d_in[1], (const float*)d_in[2],
        (const float*)d_in[3], (const float*)d_in[4], (const float*)d_in[5],
        (const float*)d_in[6], (const float*)d_in[7], (const float*)d_in[8],
        (const float*)d_in[9], (const int*)d_in[10],
        out, out + 3 * (size_t)R, out + 4 * (size_t)R, R);
}

// Round 6
// 293.668 us; speedup vs baseline: 12.7675x; 1.1704x over previous
//
#include <hip/hip_runtime.h>
#include <math.h>

// UNISURF renderer, MI355X — MFMA fp16 2-pass edition.
// One wave per ray; 4 rays / 256-thread block. Heavy evals (64 samples x
// 128->128->heads MLP) run on v_mfma_f32_16x16x32_f16 with A split into
// fp16 hi+lo (A*B = Ah*B + Al*B; W2 single fp16, rel err 2^-11 -> ~1e-3 logit).
// W2 pre-packed once per block into MFMA B-fragment order in LDS (32KB).
// R5 -> R6: N-halved accumulators (acc[4][4]) + per-half fused epilogue to
// kill the 100MB/dispatch scratch spill seen at VGPR_Count=256; bf16 3-pass
// -> fp16 2-pass (fewer MFMAs, half the W2 LDS).
//
// Verified layout (R5 passed with it):
//   A: row = lane&15,  k = 4*(lane>>4) + (e&3) + 16*(e>>2)   (e = 0..7)
//   B: col = lane&15,  same k-map
//   C: col = lane&15,  row = 4*(lane>>4) + reg

#define HID 128
#define NEARF 0.8f
#define FARF  1.8f

typedef __attribute__((ext_vector_type(8))) _Float16 half8;
typedef __attribute__((ext_vector_type(4))) float f32x4;

__device__ __forceinline__ float sigmoidf_(float x) { return 1.0f / (1.0f + expf(-x)); }

// 64-sample MLP eval on MFMA. dA0..3 = depth of sample (mt*16 + lane&15).
// f_out = raw logit (no bo). If RGB, rgb_out = feat@Wc partials.
template<bool RGB>
__device__ __forceinline__ void eval64(
    const float* __restrict__ su, const float* __restrict__ sv,
    const _Float16* __restrict__ sW2F,
    const float* __restrict__ sB2, const float* __restrict__ sWo,
    const float* __restrict__ sWc, float* __restrict__ sred,
    float dA0, float dA1, float dA2, float dA3, int lane,
    float& f_out, float* rgb_out)
{
    const int g = lane >> 4, nl = lane & 15;
    float pl[4][4], p0[4][4], p1[4][4], p2[4][4];
#pragma unroll
    for (int mt = 0; mt < 4; ++mt)
#pragma unroll
        for (int r = 0; r < 4; ++r) {
            pl[mt][r] = 0.f;
            if (RGB) { p0[mt][r] = 0.f; p1[mt][r] = 0.f; p2[mt][r] = 0.f; }
        }

#pragma unroll
    for (int nh = 0; nh < 2; ++nh) {
        f32x4 acc[4][4];
#pragma unroll
        for (int mt = 0; mt < 4; ++mt)
#pragma unroll
            for (int nt = 0; nt < 4; ++nt) acc[mt][nt] = (f32x4){0.f, 0.f, 0.f, 0.f};

#pragma unroll
        for (int kt = 0; kt < 4; ++kt) {
            const float* uk = su + kt * 32 + 4 * g;
            const float* vk = sv + kt * 32 + 4 * g;
            const float4 u0 = *reinterpret_cast<const float4*>(uk);
            const float4 u1 = *reinterpret_cast<const float4*>(uk + 16);
            const float4 v0 = *reinterpret_cast<const float4*>(vk);
            const float4 v1 = *reinterpret_cast<const float4*>(vk + 16);
            const float ue[8] = {u0.x, u0.y, u0.z, u0.w, u1.x, u1.y, u1.z, u1.w};
            const float ve[8] = {v0.x, v0.y, v0.z, v0.w, v1.x, v1.y, v1.z, v1.w};
            half8 Ah[4], Al[4];
#pragma unroll
            for (int mt = 0; mt < 4; ++mt) {
                const float d = (mt == 0) ? dA0 : (mt == 1) ? dA1 : (mt == 2) ? dA2 : dA3;
#pragma unroll
                for (int e = 0; e < 8; ++e) {
                    const float h = fmaxf(fmaf(d, ve[e], ue[e]), 0.f);
                    const _Float16 hh = (_Float16)h;
                    Ah[mt][e] = hh;
                    Al[mt][e] = (_Float16)(h - (float)hh);
                }
            }
#pragma unroll
            for (int nt = 0; nt < 4; ++nt) {
                const int frag = (kt * 8 + nh * 4 + nt) * 64 + lane;
                const half8 B = *reinterpret_cast<const half8*>(&sW2F[frag * 8]);
#pragma unroll
                for (int mt = 0; mt < 4; ++mt) {
                    acc[mt][nt] = __builtin_amdgcn_mfma_f32_16x16x32_f16(Ah[mt], B, acc[mt][nt], 0, 0, 0);
                    acc[mt][nt] = __builtin_amdgcn_mfma_f32_16x16x32_f16(Al[mt], B, acc[mt][nt], 0, 0, 0);
                }
            }
        }
        // fused epilogue for this N-half: h2 = relu(acc+b2); accumulate heads
#pragma unroll
        for (int nt = 0; nt < 4; ++nt) {
            const int j = (nh * 4 + nt) * 16 + nl;
            const float b2l = sB2[j], wol = sWo[j];
            float wc0 = 0.f, wc1 = 0.f, wc2 = 0.f;
            if (RGB) { wc0 = sWc[j * 3 + 0]; wc1 = sWc[j * 3 + 1]; wc2 = sWc[j * 3 + 2]; }
#pragma unroll
            for (int mt = 0; mt < 4; ++mt)
#pragma unroll
                for (int r = 0; r < 4; ++r) {
                    const float h2 = fmaxf(acc[mt][nt][r] + b2l, 0.f);
                    pl[mt][r] = fmaf(h2, wol, pl[mt][r]);
                    if (RGB) {
                        p0[mt][r] = fmaf(h2, wc0, p0[mt][r]);
                        p1[mt][r] = fmaf(h2, wc1, p1[mt][r]);
                        p2[mt][r] = fmaf(h2, wc2, p2[mt][r]);
                    }
                }
        }
    }

    // reduce over the 16 lanes sharing a row-group (j varies across them)
#pragma unroll
    for (int off = 1; off < 16; off <<= 1) {
#pragma unroll
        for (int mt = 0; mt < 4; ++mt)
#pragma unroll
            for (int r = 0; r < 4; ++r) {
                pl[mt][r] += __shfl_xor(pl[mt][r], off);
                if (RGB) {
                    p0[mt][r] += __shfl_xor(p0[mt][r], off);
                    p1[mt][r] += __shfl_xor(p1[mt][r], off);
                    p2[mt][r] += __shfl_xor(p2[mt][r], off);
                }
            }
    }
    // scatter to lane order via LDS (row m = mt*16 + 4*g + r)
    if (nl == 0) {
#pragma unroll
        for (int mt = 0; mt < 4; ++mt)
#pragma unroll
            for (int r = 0; r < 4; ++r) {
                const int m = mt * 16 + 4 * g + r;
                sred[m] = pl[mt][r];
                if (RGB) { sred[64 + m] = p0[mt][r]; sred[128 + m] = p1[mt][r]; sred[192 + m] = p2[mt][r]; }
            }
    }
    f_out = sred[lane];
    if (RGB) { rgb_out[0] = sred[64 + lane]; rgb_out[1] = sred[128 + lane]; rgb_out[2] = sred[192 + lane]; }
}

extern "C" __global__ void __launch_bounds__(256, 1)
unisurf_mfma_kernel(
    const float* __restrict__ raysDir, const float* __restrict__ raysOrg,
    const float* __restrict__ W1, const float* __restrict__ b1,
    const float* __restrict__ W2, const float* __restrict__ b2,
    const float* __restrict__ Wo, const float* __restrict__ bo,
    const float* __restrict__ Wc, const float* __restrict__ bc,
    const int* __restrict__ itp,
    float* __restrict__ outRGB, float* __restrict__ outD, float* __restrict__ outM,
    int nRays)
{
    __shared__ __align__(16) _Float16 sW2F[2048 * 8];   // B-frag layout fp16 (32KB)
    __shared__ __align__(16) float sU[4][HID];
    __shared__ __align__(16) float sV[4][HID];
    __shared__ __align__(16) float sH1[4][HID];
    __shared__ __align__(16) float sB2[HID];
    __shared__ __align__(16) float sWoS[HID];
    __shared__ __align__(16) float sWc[HID * 3];
    __shared__ __align__(16) float sRed[4][256];

    const int tid = threadIdx.x;
    // ---- stage W2 into MFMA B-fragment order, fp16 -------------------------
    for (int s = tid; s < 2048; s += 256) {
        const int ln = s & 63, ntg = (s >> 6) & 7, kt = s >> 9;
        const int n = ntg * 16 + (ln & 15), gg = ln >> 4;
        half8 hp;
#pragma unroll
        for (int e = 0; e < 8; ++e) {
            const int k = kt * 32 + 4 * gg + (e & 3) + ((e >> 2) << 4);
            hp[e] = (_Float16)W2[k * HID + n];
        }
        *reinterpret_cast<half8*>(&sW2F[s * 8]) = hp;
    }
    if (tid < HID) { sB2[tid] = b2[tid]; sWoS[tid] = Wo[tid]; }
    for (int i = tid; i < HID * 3; i += 256) sWc[i] = Wc[i];
    __syncthreads();

    const int w = tid >> 6, lane = tid & 63, nl = lane & 15;
    const int ray = blockIdx.x * 4 + w;
    if (ray >= nRays) return;

    // ---- per-ray setup -----------------------------------------------------
    const float ox = raysOrg[ray * 3 + 0], oy = raysOrg[ray * 3 + 1], oz = raysOrg[ray * 3 + 2];
    const float dx = raysDir[ray * 3 + 0], dy = raysDir[ray * 3 + 1], dz = raysDir[ray * 3 + 2];
    const float nrm = sqrtf(dx * dx + dy * dy + dz * dz);
    const float rdx = dx / nrm, rdy = dy / nrm, rdz = dz / nrm;
    const float bo0 = bo[0];
    const float ST = 1.0f / 127.0f;

    float* su = sU[w];
    float* sv = sV[w];
    float* sh = sH1[w];
    float* sred = sRed[w];
    for (int k = lane; k < HID; k += 64) {
        const float w1x = W1[k], w1y = W1[HID + k], w1z = W1[2 * HID + k];
        su[k] = ox * w1x + oy * w1y + oz * w1z + b1[k];
        sv[k] = rdx * w1x + rdy * w1y + rdz * w1z;
    }

    // ---- marching: chunk A (samples 0..63) ---------------------------------
    float fA;
    {
        float lg;
        eval64<false>(su, sv, sW2F, sB2, sWoS, sWc, sred,
                      NEARF + (float)(0 * 16 + nl) * ST, NEARF + (float)(1 * 16 + nl) * ST,
                      NEARF + (float)(2 * 16 + nl) * ST, NEARF + (float)(3 * 16 + nl) * ST,
                      lane, lg, nullptr);
        fA = sigmoidf_(lg + bo0) - 0.5f;
    }
    const float f0 = __shfl(fA, 0);
    const float fAn = __shfl_down(fA, 1);
    const bool crossA = (lane < 63) && (fA * fAn < 0.f);
    const unsigned long long balA = __ballot(crossA);

    int idx = 0; float f_lo = 0.f, f_hi = 0.f; bool haschange = false;
    if (balA) {
        const int l = __ffsll(balA) - 1;
        idx = l; f_lo = __shfl(fA, l); f_hi = __shfl(fA, l + 1); haschange = true;
    } else if (f0 < 0.f) {
        // ---- chunk B (samples 64..127) -------------------------------------
        float fB;
        {
            float lg;
            const float b0 = NEARF + 64.0f * ST;
            eval64<false>(su, sv, sW2F, sB2, sWoS, sWc, sred,
                          b0 + (float)(0 * 16 + nl) * ST, b0 + (float)(1 * 16 + nl) * ST,
                          b0 + (float)(2 * 16 + nl) * ST, b0 + (float)(3 * 16 + nl) * ST,
                          lane, lg, nullptr);
            fB = sigmoidf_(lg + bo0) - 0.5f;
        }
        float fprev = __shfl_up(fB, 1);
        const float fA63 = __shfl(fA, 63);
        if (lane == 0) fprev = fA63;
        const bool crossB = (fprev * fB < 0.f);   // pair s = 63 + lane
        const unsigned long long balB = __ballot(crossB);
        if (balB) {
            const int l = __ffsll(balB) - 1;
            idx = 63 + l; f_lo = __shfl(fprev, l); f_hi = __shfl(fB, l); haschange = true;
        }
    }

    // ---- secant refinement (wave-uniform; f32, W2 from global/L2) ----------
    float d_i;
    bool objmask = false;
    if (f0 >= 0.f) {
        d_i = 0.f;
    } else if (haschange && (f_lo < 0.f)) {
        float dlo = NEARF + (float)idx * ST;
        float dhi = NEARF + (float)(idx + 1) * ST;
        float flo = f_lo, fhi = f_hi;
        for (int itn = 0; itn < 8; ++itn) {
            float den = fhi - flo;
            if (fabsf(den) < 1e-12f) den = 1e-12f;
            const float dmid = dlo - flo * (dhi - dlo) / den;
            for (int k = lane; k < HID; k += 64)
                sh[k] = fmaxf(fmaf(dmid, sv[k], su[k]), 0.f);
            asm volatile("s_waitcnt lgkmcnt(0)" ::: "memory");
            __builtin_amdgcn_sched_barrier(0);
            float a0 = 0.f, a1 = 0.f;
#pragma unroll 4
            for (int k = 0; k < HID; ++k) {
                const float hk = sh[k];
                a0 = fmaf(hk, W2[k * HID + lane], a0);
                a1 = fmaf(hk, W2[k * HID + lane + 64], a1);
            }
            const float h2a = fmaxf(a0 + sB2[lane], 0.f);
            const float h2b = fmaxf(a1 + sB2[lane + 64], 0.f);
            float part = h2a * sWoS[lane] + h2b * sWoS[lane + 64];
#pragma unroll
            for (int off = 32; off; off >>= 1) part += __shfl_xor(part, off);
            const float fmid = sigmoidf_(part + bo0) - 0.5f;
            if (fmid < 0.f) { dlo = dmid; flo = fmid; }
            else            { dhi = dmid; fhi = fmid; }
        }
        float den = fhi - flo;
        if (fabsf(den) < 1e-12f) den = 1e-12f;
        d_i = dlo - flo * (dhi - dlo) / den;
        objmask = true;
    } else {
        d_i = __builtin_inff();
    }

    // ---- render: 64 samples, lane = sample ---------------------------------
    const int it = itp[0];
    const float delta = fmaxf(0.1f * expf(-2e-5f * (float)it), 0.01f);
    const float dsafe = objmask ? d_i : 1.0f;
    const float dnp = fmaxf(dsafe - delta, NEARF);
    const float dfp = fminf(dsafe + delta, FARF);
    const float t = (float)lane * (1.0f / 63.0f);
    const float depth = objmask ? (dnp * (1.f - t) + dfp * t)
                                : (NEARF * (1.f - t) + FARF * t);

    float lg, rgbacc[3];
    {
        const float dR0 = __shfl(depth, 0 * 16 + nl);
        const float dR1 = __shfl(depth, 1 * 16 + nl);
        const float dR2 = __shfl(depth, 2 * 16 + nl);
        const float dR3 = __shfl(depth, 3 * 16 + nl);
        eval64<true>(su, sv, sW2F, sB2, sWoS, sWc, sred,
                     dR0, dR1, dR2, dR3, lane, lg, rgbacc);
    }
    const float alpha = sigmoidf_(lg + bo0);
    float rc[3];
#pragma unroll
    for (int c = 0; c < 3; ++c) {
        const float x = rgbacc[c]
            + rdx * Wc[128 * 3 + c] + rdy * Wc[129 * 3 + c] + rdz * Wc[130 * 3 + c]
            + bc[c];
        rc[c] = sigmoidf_(x);
    }

    // transmittance: exclusive prefix product of (1 - alpha + 1e-6)
    const float om = 1.f - alpha + 1e-6f;
    float incl = om;
#pragma unroll
    for (int off = 1; off < 64; off <<= 1) {
        const float p = __shfl_up(incl, off);
        if (lane >= off) incl *= p;
    }
    float trans = __shfl_up(incl, 1);
    if (lane == 0) trans = 1.f;
    const float wgt = alpha * trans;

    float s0 = wgt * rc[0], s1 = wgt * rc[1], s2 = wgt * rc[2], sd = wgt * depth;
#pragma unroll
    for (int off = 32; off; off >>= 1) {
        s0 += __shfl_xor(s0, off);
        s1 += __shfl_xor(s1, off);
        s2 += __shfl_xor(s2, off);
        sd += __shfl_xor(sd, off);
    }
    if (lane == 0) {
        outRGB[ray * 3 + 0] = s0;
        outRGB[ray * 3 + 1] = s1;
        outRGB[ray * 3 + 2] = s2;
        outD[ray] = sd;
        outM[ray] = objmask ? 1.f : 0.f;
    }
}

extern "C" void kernel_launch(void* const* d_in, const int* in_sizes, int n_in,
                              void* d_out, int out_size, void* d_ws, size_t ws_size,
                              hipStream_t stream) {
    (void)n_in; (void)out_size; (void)d_ws; (void)ws_size;
    const int R = in_sizes[0] / 3;
    float* out = reinterpret_cast<float*>(d_out);
    dim3 grid((R + 3) / 4), block(256);
    hipLaunchKernelGGL(unisurf_mfma_kernel, grid, block, 0, stream,
        (const float*)d_in[0], (const float*)d_in[1], (const float*)d_in[2],
        (const float*)d_in[3], (const float*)d_in[4], (const float*)d_in[5],
        (const float*)d_in[6], (const float*)d_in[7], (const float*)d_in[8],
        (const float*)d_in[9], (const int*)d_in[10],
        out, out + 3 * (size_t)R, out + 4 * (size_t)R, R);
}